// Round 5
// baseline (806.185 us; speedup 1.0000x reference)
//
#include <hip/hip_runtime.h>
#include <hip/hip_bf16.h>

// dims (fixed): T=4, B=1024, WH=WW=8, C=256, NH=8, HD=32
// tokens per timestep G = B*64 = 65536 ; plane = G*256 = 16777216 elements
static constexpr int  G     = 65536;
static constexpr long PLANE = 16777216L;

__device__ __forceinline__ float bfh(unsigned short u) {
    union { unsigned u32; float f; } c; c.u32 = ((unsigned)u) << 16; return c.f;
}

// ---------------- prep: transposed weights into workspace ----------------
__global__ void prep_kernel(const float* __restrict__ Wq, const float* __restrict__ Wk,
                            const float* __restrict__ Wp,
                            __hip_bfloat16* __restrict__ WqT, __hip_bfloat16* __restrict__ WkT,
                            float* __restrict__ WpT)
{
    int c = blockIdx.x;      // input channel (row of transposed)
    int j = threadIdx.x;     // output channel
    int idx = c * 256 + j;
    WqT[idx] = __float2bfloat16(Wq[j * 256 + c]);
    WkT[idx] = __float2bfloat16(Wk[j * 256 + c]);
    WpT[idx] = Wp[j * 256 + c];
}

// depth-2 pipelined sparse row-gather over one 64-bit mask word (rare k-path)
__device__ __forceinline__ void gather_word(unsigned long long mm, int j, int lane,
                                            const __hip_bfloat16* __restrict__ WT,
                                            float& q0, float& q1, float& q2, float& q3)
{
    if (!mm) return;
    int b = __ffsll(mm) - 1; mm &= (mm - 1);
    ushort4 w = *((const ushort4*)(WT + (4 * b + j) * 256 + 4 * lane));
    while (mm) {
        int b2 = __ffsll(mm) - 1; mm &= (mm - 1);
        ushort4 w2 = *((const ushort4*)(WT + (4 * b2 + j) * 256 + 4 * lane));
        q0 += bfh(w.x); q1 += bfh(w.y); q2 += bfh(w.z); q3 += bfh(w.w);
        w = w2;
    }
    q0 += bfh(w.x); q1 += bfh(w.y); q2 += bfh(w.z); q3 += bfh(w.w);
}

// 8 independent chains (2 timesteps x 4 words): up to 8 loads in flight/iter.
// Masks are wave-uniform (ballot results, SGPR-resident) -> scalar branches.
__device__ __forceinline__ void gather8(
    unsigned long long m0, unsigned long long m1, unsigned long long m2, unsigned long long m3,
    unsigned long long n0, unsigned long long n1, unsigned long long n2, unsigned long long n3,
    const __hip_bfloat16* __restrict__ WT, int lane,
    float4& qa, float4& qb)
{
    const __hip_bfloat16* base = WT + 4 * lane;
    ushort4 w0 = {0,0,0,0}, w1 = {0,0,0,0}, w2 = {0,0,0,0}, w3 = {0,0,0,0};
    ushort4 x0 = {0,0,0,0}, x1 = {0,0,0,0}, x2 = {0,0,0,0}, x3 = {0,0,0,0};
    while (m0 | m1 | m2 | m3 | n0 | n1 | n2 | n3) {
        bool h0 = m0 != 0, h1 = m1 != 0, h2 = m2 != 0, h3 = m3 != 0;
        bool g0 = n0 != 0, g1 = n1 != 0, g2 = n2 != 0, g3 = n3 != 0;
        if (h0) { int b = __ffsll(m0) - 1; m0 &= m0 - 1; w0 = *(const ushort4*)(base + (4*b+0)*256); }
        if (h1) { int b = __ffsll(m1) - 1; m1 &= m1 - 1; w1 = *(const ushort4*)(base + (4*b+1)*256); }
        if (h2) { int b = __ffsll(m2) - 1; m2 &= m2 - 1; w2 = *(const ushort4*)(base + (4*b+2)*256); }
        if (h3) { int b = __ffsll(m3) - 1; m3 &= m3 - 1; w3 = *(const ushort4*)(base + (4*b+3)*256); }
        if (g0) { int b = __ffsll(n0) - 1; n0 &= n0 - 1; x0 = *(const ushort4*)(base + (4*b+0)*256); }
        if (g1) { int b = __ffsll(n1) - 1; n1 &= n1 - 1; x1 = *(const ushort4*)(base + (4*b+1)*256); }
        if (g2) { int b = __ffsll(n2) - 1; n2 &= n2 - 1; x2 = *(const ushort4*)(base + (4*b+2)*256); }
        if (g3) { int b = __ffsll(n3) - 1; n3 &= n3 - 1; x3 = *(const ushort4*)(base + (4*b+3)*256); }
        if (h0) { qa.x += bfh(w0.x); qa.y += bfh(w0.y); qa.z += bfh(w0.z); qa.w += bfh(w0.w); }
        if (h1) { qa.x += bfh(w1.x); qa.y += bfh(w1.y); qa.z += bfh(w1.z); qa.w += bfh(w1.w); }
        if (h2) { qa.x += bfh(w2.x); qa.y += bfh(w2.y); qa.z += bfh(w2.z); qa.w += bfh(w2.w); }
        if (h3) { qa.x += bfh(w3.x); qa.y += bfh(w3.y); qa.z += bfh(w3.z); qa.w += bfh(w3.w); }
        if (g0) { qb.x += bfh(x0.x); qb.y += bfh(x0.y); qb.z += bfh(x0.z); qb.w += bfh(x0.w); }
        if (g1) { qb.x += bfh(x1.x); qb.y += bfh(x1.y); qb.z += bfh(x1.z); qb.w += bfh(x1.w); }
        if (g2) { qb.x += bfh(x2.x); qb.y += bfh(x2.y); qb.z += bfh(x2.z); qb.w += bfh(x2.w); }
        if (g3) { qb.x += bfh(x3.x); qb.y += bfh(x3.y); qb.z += bfh(x3.z); qb.w += bfh(x3.w); }
    }
}

// ============ fully fused kernel ============
// Block p owns tokens [p*256, p*256+256). Index algebra (verified R0 mapping):
// output batch b2 needs AM flat rows [b2*256, b2*256+256) = exactly tokens of
// group p=(b2&255) at t=(b2>>8). So block p computes AM for its tokens into LDS
// and writes y/attn_out for batches b2 = tt*256+p, tt=0..3 — fully self-contained.
// Bit-exact LIF: v = v + (x-v)*0.5, spike = (v-1 >= 0), hard reset.
// attn_out ≡ 0 proved: x2 in {0,1}, v'=(v+x)/2 < 1 strictly (exact dyadic fp32).
__global__ __launch_bounds__(1024) void fused_kernel(
    const float* __restrict__ x,
    const __hip_bfloat16* __restrict__ WqT,
    const __hip_bfloat16* __restrict__ WkT,
    const float* __restrict__ WpT,
    const float* __restrict__ bp,
    const float* __restrict__ pos,
    float* __restrict__ y,
    float* __restrict__ attn_out)
{
    __shared__ unsigned AMs[1024 * 8];    // 32 KB: [(t*256 + tl)*8 + wd]
    __shared__ unsigned anyflag;

    int p    = blockIdx.x;                // token group 0..255
    int lane = threadIdx.x & 63;
    int wv   = threadIdx.x >> 6;          // 0..15
    int sh   = (lane & 56);               // 8*(lane>>3)
    long g0  = (long)p * 256;

    if (threadIdx.x == 0) anyflag = 0u;
    __syncthreads();

    // ---------------- phase 1: compute AM for 256 tokens (16/wave) ----------------
    for (int gi = 0; gi < 16; ++gi) {
        int  tl = wv * 16 + gi;           // local token 0..255
        long g  = g0 + tl;
        int  hw = (int)g & 63;

        float4 X[4];
        #pragma unroll
        for (int t = 0; t < 4; ++t)
            X[t] = ((const float4*)(x + (long)t * PLANE + g * 256))[lane];

        // input-spike masks (pure VALU + ballots)
        unsigned long long sm[4][4];
        float4 v = make_float4(0.f, 0.f, 0.f, 0.f);
        #pragma unroll
        for (int t = 0; t < 4; ++t) {
            v.x = v.x + (X[t].x - v.x) * 0.5f; bool s0 = (v.x - 1.0f) >= 0.0f; if (s0) v.x = 0.f;
            v.y = v.y + (X[t].y - v.y) * 0.5f; bool s1 = (v.y - 1.0f) >= 0.0f; if (s1) v.y = 0.f;
            v.z = v.z + (X[t].z - v.z) * 0.5f; bool s2 = (v.z - 1.0f) >= 0.0f; if (s2) v.z = 0.f;
            v.w = v.w + (X[t].w - v.w) * 0.5f; bool s3 = (v.w - 1.0f) >= 0.0f; if (s3) v.w = 0.f;
            sm[t][0] = __ballot(s0);
            sm[t][1] = __ballot(s1);
            sm[t][2] = __ballot(s2);
            sm[t][3] = __ballot(s3);
        }

        // sparse q gathers, 8 chains in flight
        float4 qs0 = make_float4(0.f,0.f,0.f,0.f), qs1 = make_float4(0.f,0.f,0.f,0.f);
        float4 qs2 = make_float4(0.f,0.f,0.f,0.f), qs3 = make_float4(0.f,0.f,0.f,0.f);
        gather8(sm[0][0], sm[0][1], sm[0][2], sm[0][3],
                sm[1][0], sm[1][1], sm[1][2], sm[1][3], WqT, lane, qs0, qs1);
        gather8(sm[2][0], sm[2][1], sm[2][2], sm[2][3],
                sm[3][0], sm[3][1], sm[3][2], sm[3][3], WqT, lane, qs2, qs3);

        // q LIF + att-token LIF (identical arithmetic to prior rounds)
        float4 vq = make_float4(0.f, 0.f, 0.f, 0.f);
        float  va = 0.f;
        unsigned attb = 0u;
        #pragma unroll
        for (int t = 0; t < 4; ++t) {
            float4 q = (t == 0) ? qs0 : (t == 1) ? qs1 : (t == 2) ? qs2 : qs3;
            vq.x = vq.x + (q.x - vq.x) * 0.5f; bool t0 = (vq.x - 1.0f) >= 0.0f; if (t0) vq.x = 0.f;
            vq.y = vq.y + (q.y - vq.y) * 0.5f; bool t1 = (vq.y - 1.0f) >= 0.0f; if (t1) vq.y = 0.f;
            vq.z = vq.z + (q.z - vq.z) * 0.5f; bool t2 = (vq.z - 1.0f) >= 0.0f; if (t2) vq.z = 0.f;
            vq.w = vq.w + (q.w - vq.w) * 0.5f; bool t3 = (vq.w - 1.0f) >= 0.0f; if (t3) vq.w = 0.f;
            unsigned long long qb0 = __ballot(t0);
            unsigned long long qb1 = __ballot(t1);
            unsigned long long qb2 = __ballot(t2);
            unsigned long long qb3 = __ballot(t3);

            int cnt = __popc((unsigned)((qb0 >> sh) & 0xFFull))
                    + __popc((unsigned)((qb1 >> sh) & 0xFFull))
                    + __popc((unsigned)((qb2 >> sh) & 0xFFull))
                    + __popc((unsigned)((qb3 >> sh) & 0xFFull));
            va = va + ((float)cnt - va) * 0.5f;
            bool a = (va - 1.0f) >= 0.0f; if (a) va = 0.f;
            attb |= (a ? 1u : 0u) << t;
        }

        bool anyatt = (__ballot(attb != 0u) != 0ull);
        if (!anyatt) {
            if (lane < 32) {
                int t = lane >> 3, wd = lane & 7;
                AMs[(t * 256 + tl) * 8 + wd] = 0u;
            }
        } else {
            // rare: full k path (wave-uniform)
            if (lane == 0) anyflag = 1u;
            float4 vk = make_float4(0.f, 0.f, 0.f, 0.f);
            #pragma unroll
            for (int t = 0; t < 4; ++t) {
                float k0 = 0.f, k1 = 0.f, k2 = 0.f, k3 = 0.f;
                #pragma unroll
                for (int j = 0; j < 4; ++j)
                    gather_word(sm[t][j], j, lane, WkT, k0, k1, k2, k3);
                float4 pp = ((const float4*)(pos + t * 16384 + hw * 256))[lane];
                k0 += pp.x; k1 += pp.y; k2 += pp.z; k3 += pp.w;

                vk.x = vk.x + (k0 - vk.x) * 0.5f; bool t0 = (vk.x - 1.0f) >= 0.0f; if (t0) vk.x = 0.f;
                vk.y = vk.y + (k1 - vk.y) * 0.5f; bool t1 = (vk.y - 1.0f) >= 0.0f; if (t1) vk.y = 0.f;
                vk.z = vk.z + (k2 - vk.z) * 0.5f; bool t2 = (vk.z - 1.0f) >= 0.0f; if (t2) vk.z = 0.f;
                vk.w = vk.w + (k3 - vk.w) * 0.5f; bool t3 = (vk.w - 1.0f) >= 0.0f; if (t3) vk.w = 0.f;

                bool at = ((attb >> t) & 1u) != 0u;
                unsigned long long bb[4];
                bb[0] = __ballot(t0 && at);
                bb[1] = __ballot(t1 && at);
                bb[2] = __ballot(t2 && at);
                bb[3] = __ballot(t3 && at);
                if (lane < 8) {
                    unsigned wdv = 0u;
                    #pragma unroll
                    for (int hd = 0; hd < 32; ++hd) {
                        int ls = lane * 8 + (hd >> 2);
                        wdv |= (unsigned)((bb[hd & 3] >> ls) & 1ull) << hd;
                    }
                    AMs[(t * 256 + tl) * 8 + lane] = wdv;
                }
            }
        }
    }

    __syncthreads();

    // ---------------- phase 2: outputs for batches b2 = tt*256+p ----------------
    // wave wv -> tt = wv>>2, t2 = wv&3 ; rows i=hw2 0..63 (contiguous 64 KB)
    int tt = wv >> 2;
    int t2 = wv & 3;
    long rowbase = (long)t2 * 65536 + ((long)tt * 256 + p) * 64;
    float4* yp = (float4*)y        + rowbase * 64 + lane;
    float4* ap = (float4*)attn_out + rowbase * 64 + lane;
    float4 base = ((const float4*)bp)[lane];
    const float4 z = make_float4(0.f, 0.f, 0.f, 0.f);

    if (anyflag == 0u) {
        #pragma unroll 8
        for (int i = 0; i < 64; ++i) yp[i * 64] = base;
        #pragma unroll 8
        for (int i = 0; i < 64; ++i) ap[i * 64] = z;
    } else {
        for (int i = 0; i < 64; ++i) {
            float4 val = base;
            #pragma unroll 1
            for (int nh = 0; nh < 8; ++nh) {
                unsigned W = AMs[(tt * 256 + (nh >> 1) * 64 + (nh & 1) * 32 + t2 * 8 + (i >> 3)) * 8 + (i & 7)];
                while (W) {
                    int hd = __ffs(W) - 1;
                    W &= (W - 1);
                    float4 wl = ((const float4*)WpT)[(nh * 32 + hd) * 64 + lane];
                    val.x += wl.x; val.y += wl.y; val.z += wl.z; val.w += wl.w;
                }
            }
            yp[i * 64] = val;
            ap[i * 64] = z;
        }
    }
}

extern "C" void kernel_launch(void* const* d_in, const int* in_sizes, int n_in,
                              void* d_out, int out_size, void* d_ws, size_t ws_size,
                              hipStream_t stream) {
    const float* x   = (const float*)d_in[0];
    const float* Wq  = (const float*)d_in[1];
    const float* Wk  = (const float*)d_in[2];
    const float* Wp  = (const float*)d_in[3];
    const float* bp  = (const float*)d_in[4];
    const float* pos = (const float*)d_in[5];

    float* y        = (float*)d_out;
    float* attn_out = y + 67108864L;

    char* ws = (char*)d_ws;
    __hip_bfloat16* WqT = (__hip_bfloat16*)(ws);
    __hip_bfloat16* WkT = (__hip_bfloat16*)(ws + (128L << 10));
    float*          WpT = (float*)(ws + (256L << 10));

    prep_kernel<<<256, 256, 0, stream>>>(Wq, Wk, Wp, WqT, WkT, WpT);
    fused_kernel<<<256, 1024, 0, stream>>>(x, WqT, WkT, WpT, bp, pos, y, attn_out);
}